// Round 9
// baseline (130.293 us; speedup 1.0000x reference)
//
#include <hip/hip_runtime.h>
#include <hip/hip_bf16.h>

// E3nnSimpleEdgeBlock via 32x32x16 bf16 MFMA. R5-proven skeleton (2 edge-tiles
// x 2 v-halves, LDS partial-sum reduce), but M=32 edges and N=32 w's per MFMA
// fragment: the 10 B-fragment L2 loads + 1 b ds_read per v now serve 32 edges
// (2x arithmetic intensity vs R5), and each iteration carries ~2x independent
// VALU to hide load latency under.
//
//   out0[e,w]   = C0*( sum_uv W000[u,v,w] a0[u]b0[v] + IS3 * sum_uv W110[u,v,w] dot(a1[u],b1[v]) )
//   out1[e,w,k] = C1*( IS3*( sum W011 a0[u]b1[v,k] + sum W101 a1[u,k]b0[v] ) + IS6*sum W111 cross_k )
//
// mfma_f32_32x32x16_bf16 lane mapping (C/D m74/m101-verified; A/B mirror 16x16):
//   A[row=l&31][k=8*(l>>5)+j]  B[k=8*(l>>5)+j][col=l&31]
//   D[col=l&31][row=(r&3)+8*(r>>2)+4*(l>>5)], r=0..15

typedef __attribute__((ext_vector_type(8)))  short short8;   // 8 bf16 (4 VGPRs)
typedef __attribute__((ext_vector_type(16))) float f32x16;   // 32x32 accumulator

static constexpr float C_OUT0    = 0.022097086912079608f; // 1/sqrt(2048)
static constexpr float C_OUT1    = 0.03125f;              // 1/sqrt(1024)
static constexpr float INV_SQRT3 = 0.57735026918962576f;
static constexpr float INV_SQRT6 = 0.40824829046386302f;

static __device__ __forceinline__ short bfbits(float x) {
    __hip_bfloat16 h = __float2bfloat16(x);
    return __builtin_bit_cast(short, h);
}

// ---------------------------------------------------------------------------
// prep: bf16 B-fragment stream for the 32x32x16 shape.
// Stream: for v in 0..31, frag f in 0..9, lane l in 0..63: 8 bf16 = 16 B.
//   f = 2g + h;  g: 0=W000 1=W110 2=W011 3=W101 4=W111;  h = (u>>4) K-half
//   l = ((u>>3)&1)*32 + w  (w = 0..31);  j = u&7
//   value = scale_g * Wg[u*1024 + v*32 + w].  Total 327680 B.
// ---------------------------------------------------------------------------
__global__ __launch_bounds__(256) void prep_weights(
    const float* __restrict__ W000, const float* __restrict__ W110,
    const float* __restrict__ W011, const float* __restrict__ W101,
    const float* __restrict__ W111, short* __restrict__ wsB)
{
    const int t = blockIdx.x * 256 + threadIdx.x;   // 0 .. 5*32768-1
    if (t >= 5 * 32768) return;
    const int g   = t >> 15;
    const int idx = t & 32767;          // u*1024 + v*32 + w
    const int u = idx >> 10, v = (idx >> 5) & 31, w = idx & 31;
    const float* Wp = (g == 0) ? W000 : (g == 1) ? W110 : (g == 2) ? W011
                    : (g == 3) ? W101 : W111;
    const float s = (g == 0) ? C_OUT0
                  : (g == 1) ? C_OUT0 * INV_SQRT3
                  : (g == 4) ? C_OUT1 * INV_SQRT6
                  :            C_OUT1 * INV_SQRT3;
    const int h = (u >> 4) & 1;
    const int f = 2 * g + h;
    const int l = (((u >> 3) & 1) << 5) | w;
    const int j = u & 7;
    wsB[(((v * 10 + f) * 64) + l) * 8 + j] = bfbits(s * Wp[idx]);
}

// ---------------------------------------------------------------------------
// main: 256 threads = 4 waves = 2 edge-tiles (32 edges) x 2 v-halves.
// LDS 33792 B time-multiplexed: x1 stage [64][33 float4] -> bs[e][v] float4
// {b0,b1x,b1y,b1z} (stride 33) -> reduction scratch (c-major, conflict-free).
// ---------------------------------------------------------------------------
__global__ __launch_bounds__(256) void e3nn_m32(
    const float* __restrict__ x1, const float* __restrict__ x2,
    const short8* __restrict__ wsB, float* __restrict__ out, int E)
{
    __shared__ __align__(16) float smemf[64 * 132];   // 33792 B
    float4* smem4 = (float4*)smemf;

    const int tid   = threadIdx.x;
    const int l     = tid & 63;
    const int wv    = tid >> 6;
    const int tile  = wv & 1;    // edge-tile (32 edges) within block
    const int vh    = wv >> 1;   // v-half: 0 -> v 0..15, 1 -> v 16..31
    const int eBase = blockIdx.x * 64;

    // ---- phase 1: stage x1 tile (64 edges x 32 float4), padded stride 33 ----
    const float4* x1v = (const float4*)x1;
    for (int i = tid; i < 64 * 32; i += 256) {
        const int e = i >> 5, c4 = i & 31;
        float4 val = {0.f, 0.f, 0.f, 0.f};
        if (eBase + e < E) val = x1v[(size_t)(eBase + e) * 32 + c4];
        smem4[e * 33 + c4] = val;
    }
    __syncthreads();

    // ---- hoist per-lane a-values (f32): edge = l&31, k-group = l>>5 ----
    const int erow = l & 31;   // A-row edge; also D column w in epilogue
    const int kg   = l >> 5;
    const float* row = smemf + (tile * 32 + erow) * 132;
    float a0r[2][8], a1r[3][2][8];
    #pragma unroll
    for (int h = 0; h < 2; ++h)
        #pragma unroll
        for (int j = 0; j < 8; ++j) {
            const int u = 16 * h + 8 * kg + j;
            a0r[h][j]    = row[u];
            a1r[0][h][j] = row[32 + 3 * u + 0];
            a1r[1][h][j] = row[32 + 3 * u + 1];
            a1r[2][h][j] = row[32 + 3 * u + 2];
        }
    __syncthreads();   // x1 stage dead

    // ---- phase 2: bs[e][v] = {b0, b1x, b1y, b1z} f32, stride 33 float4 ----
    for (int i = tid; i < 64 * 128; i += 256) {
        const int e = i >> 7, r = i & 127;
        float val = 0.f;
        if (eBase + e < E) val = x2[(size_t)(eBase + e) * 128 + r];
        if (r < 32) {
            smemf[e * 132 + r * 4] = val;
        } else {
            const int q = r - 32, vv = q / 3, c = q - 3 * vv;
            smemf[e * 132 + vv * 4 + 1 + c] = val;
        }
    }
    __syncthreads();

    // ---- main v loop over this wave's half: 16 iters, 22 MFMAs each ----
    const f32x16 zero16 = {0.f,0.f,0.f,0.f,0.f,0.f,0.f,0.f,
                           0.f,0.f,0.f,0.f,0.f,0.f,0.f,0.f};
    f32x16 acc0    = zero16;
    f32x16 acc1[3] = {zero16, zero16, zero16};

    const short8* wb    = wsB + l;
    const float4* bsrow = smem4 + (tile * 32 + erow) * 33;

    for (int i = 0; i < 16; ++i) {
        const int v = vh * 16 + i;
        const float4 b = bsrow[v];
        const short8* p = wb + v * 640;   // (v*10 + f)*64 + l
        short8 Bf[10];
        #pragma unroll
        for (int f = 0; f < 10; ++f) Bf[f] = p[f * 64];

        const float bv[3] = {b.y, b.z, b.w};

        #pragma unroll
        for (int h = 0; h < 2; ++h) {
            short8 A;
            // out0 ch0: a0[u]*b0 -> W000
            #pragma unroll
            for (int j = 0; j < 8; ++j) A[j] = bfbits(a0r[h][j] * b.x);
            acc0 = __builtin_amdgcn_mfma_f32_32x32x16_bf16(A, Bf[0 + h], acc0, 0, 0, 0);
            // out0 ch1: dot(a1,b1) -> W110
            #pragma unroll
            for (int j = 0; j < 8; ++j)
                A[j] = bfbits(a1r[0][h][j] * b.y + a1r[1][h][j] * b.z + a1r[2][h][j] * b.w);
            acc0 = __builtin_amdgcn_mfma_f32_32x32x16_bf16(A, Bf[2 + h], acc0, 0, 0, 0);
            // out1 component kx
            #pragma unroll
            for (int kx = 0; kx < 3; ++kx) {
                const int ii = (kx + 1) % 3, jj = (kx + 2) % 3;
                short8 A011, A101, A111;
                #pragma unroll
                for (int j = 0; j < 8; ++j) {
                    A011[j] = bfbits(a0r[h][j] * bv[kx]);
                    A101[j] = bfbits(a1r[kx][h][j] * b.x);
                    A111[j] = bfbits(a1r[ii][h][j] * bv[jj] - a1r[jj][h][j] * bv[ii]);
                }
                acc1[kx] = __builtin_amdgcn_mfma_f32_32x32x16_bf16(A011, Bf[4 + h], acc1[kx], 0, 0, 0);
                acc1[kx] = __builtin_amdgcn_mfma_f32_32x32x16_bf16(A101, Bf[6 + h], acc1[kx], 0, 0, 0);
                acc1[kx] = __builtin_amdgcn_mfma_f32_32x32x16_bf16(A111, Bf[8 + h], acc1[kx], 0, 0, 0);
            }
        }
    }

    // ---- reduce the two v-halves through LDS (c-major scratch, no conflicts) ----
    __syncthreads();   // all waves past their bs reads; safe to overwrite

    float* red = smemf;
    const int w = erow;   // D column
    if (vh == 1) {
        #pragma unroll
        for (int r = 0; r < 16; ++r) {
            const int eloc = tile * 32 + (r & 3) + 8 * (r >> 2) + 4 * kg;
            red[eloc * 132 + 0 * 33 + w] = acc0[r];
            red[eloc * 132 + 1 * 33 + w] = acc1[0][r];
            red[eloc * 132 + 2 * 33 + w] = acc1[1][r];
            red[eloc * 132 + 3 * 33 + w] = acc1[2][r];
        }
    }
    __syncthreads();

    // ---- epilogue from vh=0 waves (scales pre-baked into weights) ----
    if (vh == 0) {
        #pragma unroll
        for (int r = 0; r < 16; ++r) {
            const int eloc = tile * 32 + (r & 3) + 8 * (r >> 2) + 4 * kg;
            const int ge = eBase + eloc;
            if (ge < E) {
                const size_t base = (size_t)ge * 128;
                out[base + w]              = acc0[r]    + red[eloc * 132 + 0 * 33 + w];
                out[base + 32 + 3 * w + 0] = acc1[0][r] + red[eloc * 132 + 1 * 33 + w];
                out[base + 32 + 3 * w + 1] = acc1[1][r] + red[eloc * 132 + 2 * 33 + w];
                out[base + 32 + 3 * w + 2] = acc1[2][r] + red[eloc * 132 + 3 * 33 + w];
            }
        }
    }
}

extern "C" void kernel_launch(void* const* d_in, const int* in_sizes, int n_in,
                              void* d_out, int out_size, void* d_ws, size_t ws_size,
                              hipStream_t stream) {
    const float* x1   = (const float*)d_in[0];
    const float* x2   = (const float*)d_in[1];
    const float* W000 = (const float*)d_in[2];
    const float* W110 = (const float*)d_in[3];
    const float* W011 = (const float*)d_in[4];
    const float* W101 = (const float*)d_in[5];
    const float* W111 = (const float*)d_in[6];
    float* out = (float*)d_out;

    const int E = in_sizes[0] / 128;

    hipLaunchKernelGGL(prep_weights, dim3((5 * 32768 + 255) / 256), dim3(256), 0, stream,
                       W000, W110, W011, W101, W111, (short*)d_ws);

    const int grid = (E + 63) / 64;
    hipLaunchKernelGGL(e3nn_m32, dim3(grid), dim3(256), 0, stream,
                       x1, x2, (const short8*)d_ws, out, E);
}

// Round 10
// 81.082 us; speedup vs baseline: 1.6069x; 1.6069x over previous
//
#include <hip/hip_runtime.h>
#include <hip/hip_bf16.h>

// E3nnSimpleEdgeBlock via bf16 MFMA. R5-proven skeleton (2 edge-tiles x 2
// v-halves, LDS partial-sum reduce) + ONE delta: #pragma unroll 4 on the
// v-loop so the compiler pipelines B-fragment loads across iterations
// (counted-vmcnt prefetch without manual register choreography).
//
//   out0[e,w]   = C0*( sum_uv W000[u,v,w] a0[u]b0[v] + IS3 * sum_uv W110[u,v,w] dot(a1[u],b1[v]) )
//   out1[e,w,k] = C1*( IS3*( sum W011 a0[u]b1[v,k] + sum W101 a1[u,k]b0[v] ) + IS6*sum W111 cross_k )
//
// mfma_f32_16x16x32_bf16 lane mapping (m89-verified):
//   A[row=l&15][k=8*(l>>4)+j]  B[k=8*(l>>4)+j][col=l&15]  D[row=4*(l>>4)+r][col=l&15]

typedef __attribute__((ext_vector_type(8))) short short8;   // 8 bf16 (4 VGPRs)
typedef __attribute__((ext_vector_type(4))) float f32x4;

static constexpr float C_OUT0    = 0.022097086912079608f; // 1/sqrt(2048)
static constexpr float C_OUT1    = 0.03125f;              // 1/sqrt(1024)
static constexpr float INV_SQRT3 = 0.57735026918962576f;
static constexpr float INV_SQRT6 = 0.40824829046386302f;

static __device__ __forceinline__ short bfbits(float x) {
    __hip_bfloat16 h = __float2bfloat16(x);
    return __builtin_bit_cast(short, h);
}

// ---------------------------------------------------------------------------
// prep (unchanged, post-timing-proven x3): bf16 B-fragment stream in d_ws.
// Layout: for v, frag f (0..9), lane l: 8 bf16 = 16 B. Slice per v = 10240 B.
//   f = 2g + nf;  g: 0=W000 1=W110 2=W011 3=W101 4=W111;  w = nf*16 + (l&15)
//   element j: scale_g * Wg[(8*(l>>4)+j)*1024 + v*32 + w].  Total 327680 B.
// ---------------------------------------------------------------------------
__global__ __launch_bounds__(256) void prep_weights(
    const float* __restrict__ W000, const float* __restrict__ W110,
    const float* __restrict__ W011, const float* __restrict__ W101,
    const float* __restrict__ W111, short* __restrict__ wsB)
{
    const int t = blockIdx.x * 256 + threadIdx.x;   // 0 .. 5*32768-1
    if (t >= 5 * 32768) return;
    const int g   = t >> 15;
    const int idx = t & 32767;          // u*1024 + v*32 + w
    const int u = idx >> 10, v = (idx >> 5) & 31, w = idx & 31;
    const float* Wp = (g == 0) ? W000 : (g == 1) ? W110 : (g == 2) ? W011
                    : (g == 3) ? W101 : W111;
    const float s = (g == 0) ? C_OUT0
                  : (g == 1) ? C_OUT0 * INV_SQRT3
                  : (g == 4) ? C_OUT1 * INV_SQRT6
                  :            C_OUT1 * INV_SQRT3;
    const int f = 2 * g + (w >> 4);
    const int l = ((u >> 3) << 4) | (w & 15);
    const int j = u & 7;
    wsB[(((v * 10 + f) * 64) + l) * 8 + j] = bfbits(s * Wp[idx]);
}

// ---------------------------------------------------------------------------
// main: 256 threads = 4 waves = 2 edge-tiles (t) x 2 v-halves (vh).
// LDS 16896 B time-multiplexed: x1 stage [32][33 float4] -> bs[e][v] float4
// {b0,b1x,b1y,b1z} (stride 33) -> reduction scratch.
// ---------------------------------------------------------------------------
__global__ __launch_bounds__(256) void e3nn_u4(
    const float* __restrict__ x1, const float* __restrict__ x2,
    const short8* __restrict__ wsB, float* __restrict__ out, int E)
{
    __shared__ __align__(16) float smemf[32 * 132];   // 16896 B
    float4* smem4 = (float4*)smemf;

    const int tid   = threadIdx.x;
    const int l     = tid & 63;
    const int wv    = tid >> 6;
    const int t     = wv & 1;    // edge-tile within block
    const int vh    = wv >> 1;   // v-half: 0 -> v 0..15, 1 -> v 16..31
    const int eBase = blockIdx.x * 32;

    // ---- phase 1: stage x1 tile (32 edges x 32 float4), padded stride 33 ----
    const float4* x1v = (const float4*)x1;
    for (int i = tid; i < 32 * 32; i += 256) {
        const int e = i >> 5, c4 = i & 31;
        float4 val = {0.f, 0.f, 0.f, 0.f};
        if (eBase + e < E) val = x1v[(size_t)(eBase + e) * 32 + c4];
        smem4[e * 33 + c4] = val;
    }
    __syncthreads();

    // ---- hoist per-lane a-values (f32) into registers ----
    const int eloc = l & 15;
    const int u0   = (l >> 4) * 8;
    const float* row = smemf + (t * 16 + eloc) * 132;
    float a0r[8], a1r[3][8];
    #pragma unroll
    for (int j = 0; j < 8; ++j) {
        a0r[j] = row[u0 + j];
        #pragma unroll
        for (int c = 0; c < 3; ++c)
            a1r[c][j] = row[32 + 3 * (u0 + j) + c];
    }
    __syncthreads();   // x1 stage dead

    // ---- phase 2: bs[e][v] = {b0, b1x, b1y, b1z} f32, stride 33 float4 ----
    for (int i = tid; i < 32 * 128; i += 256) {
        const int e = i >> 7, r = i & 127;
        float val = 0.f;
        if (eBase + e < E) val = x2[(size_t)(eBase + e) * 128 + r];
        if (r < 32) {
            smemf[e * 132 + r * 4] = val;
        } else {
            const int q = r - 32, vv = q / 3, c = q - 3 * vv;
            smemf[e * 132 + vv * 4 + 1 + c] = val;
        }
    }
    __syncthreads();

    // ---- v-loop over this wave's half: 16 iters, unroll 4 for load pipelining ----
    const f32x4 zero = {0.f, 0.f, 0.f, 0.f};
    f32x4 acc0[2]    = {zero, zero};
    f32x4 acc1[3][2] = {{zero, zero}, {zero, zero}, {zero, zero}};

    const short8* wb    = wsB + l;
    const float4* bsrow = smem4 + (t * 16 + eloc) * 33;

    #pragma unroll 4
    for (int v = vh * 16; v < vh * 16 + 16; ++v) {
        const float4 b = bsrow[v];
        const short8* p = wb + v * 640;   // (v*10 + f)*64 + l
        short8 Bf[10];
        #pragma unroll
        for (int i = 0; i < 10; ++i) Bf[i] = p[i * 64];

        const float bv[3] = {b.y, b.z, b.w};
        short8 A;

        // out0 ch0: a0[u]*b0[v]
        #pragma unroll
        for (int j = 0; j < 8; ++j) A[j] = bfbits(a0r[j] * b.x);
        acc0[0] = __builtin_amdgcn_mfma_f32_16x16x32_bf16(A, Bf[0], acc0[0], 0, 0, 0);
        acc0[1] = __builtin_amdgcn_mfma_f32_16x16x32_bf16(A, Bf[1], acc0[1], 0, 0, 0);

        // out0 ch1: dot(a1[u], b1[v])
        #pragma unroll
        for (int j = 0; j < 8; ++j)
            A[j] = bfbits(a1r[0][j] * b.y + a1r[1][j] * b.z + a1r[2][j] * b.w);
        acc0[0] = __builtin_amdgcn_mfma_f32_16x16x32_bf16(A, Bf[2], acc0[0], 0, 0, 0);
        acc0[1] = __builtin_amdgcn_mfma_f32_16x16x32_bf16(A, Bf[3], acc0[1], 0, 0, 0);

        // out1 component kx
        #pragma unroll
        for (int kx = 0; kx < 3; ++kx) {
            const int ii = (kx + 1) % 3, jj = (kx + 2) % 3;
            short8 A011, A101, A111;
            #pragma unroll
            for (int j = 0; j < 8; ++j) {
                A011[j] = bfbits(a0r[j] * bv[kx]);
                A101[j] = bfbits(a1r[kx][j] * b.x);
                A111[j] = bfbits(a1r[ii][j] * bv[jj] - a1r[jj][j] * bv[ii]);
            }
            acc1[kx][0] = __builtin_amdgcn_mfma_f32_16x16x32_bf16(A011, Bf[4], acc1[kx][0], 0, 0, 0);
            acc1[kx][1] = __builtin_amdgcn_mfma_f32_16x16x32_bf16(A011, Bf[5], acc1[kx][1], 0, 0, 0);
            acc1[kx][0] = __builtin_amdgcn_mfma_f32_16x16x32_bf16(A101, Bf[6], acc1[kx][0], 0, 0, 0);
            acc1[kx][1] = __builtin_amdgcn_mfma_f32_16x16x32_bf16(A101, Bf[7], acc1[kx][1], 0, 0, 0);
            acc1[kx][0] = __builtin_amdgcn_mfma_f32_16x16x32_bf16(A111, Bf[8], acc1[kx][0], 0, 0, 0);
            acc1[kx][1] = __builtin_amdgcn_mfma_f32_16x16x32_bf16(A111, Bf[9], acc1[kx][1], 0, 0, 0);
        }
    }

    // ---- reduce the two v-halves through LDS (stride-33 rows) ----
    __syncthreads();   // all waves past their LDS b-reads

    float* red = smemf;
    const int rbase = (t * 64 + l) * 33;   // max 127*33+31 = 4222 < 4224
    if (vh == 1) {
        #pragma unroll
        for (int nf = 0; nf < 2; ++nf)
            #pragma unroll
            for (int r = 0; r < 4; ++r) {
                red[rbase + (0 + nf) * 4 + r] = acc0[nf][r];
                red[rbase + (2 + nf) * 4 + r] = acc1[0][nf][r];
                red[rbase + (4 + nf) * 4 + r] = acc1[1][nf][r];
                red[rbase + (6 + nf) * 4 + r] = acc1[2][nf][r];
            }
    }
    __syncthreads();

    // ---- epilogue from vh=0 waves (scales pre-baked into weights) ----
    if (vh == 0) {
        const int be0 = t * 16 + (l >> 4) * 4;
        #pragma unroll
        for (int nf = 0; nf < 2; ++nf) {
            const int w = nf * 16 + (l & 15);
            #pragma unroll
            for (int r = 0; r < 4; ++r) {
                const int ge = eBase + be0 + r;
                if (ge < E) {
                    const size_t base = (size_t)ge * 128;
                    out[base + w] =
                        acc0[nf][r] + red[rbase + (0 + nf) * 4 + r];
                    out[base + 32 + 3 * w + 0] =
                        acc1[0][nf][r] + red[rbase + (2 + nf) * 4 + r];
                    out[base + 32 + 3 * w + 1] =
                        acc1[1][nf][r] + red[rbase + (4 + nf) * 4 + r];
                    out[base + 32 + 3 * w + 2] =
                        acc1[2][nf][r] + red[rbase + (6 + nf) * 4 + r];
                }
            }
        }
    }
}

extern "C" void kernel_launch(void* const* d_in, const int* in_sizes, int n_in,
                              void* d_out, int out_size, void* d_ws, size_t ws_size,
                              hipStream_t stream) {
    const float* x1   = (const float*)d_in[0];
    const float* x2   = (const float*)d_in[1];
    const float* W000 = (const float*)d_in[2];
    const float* W110 = (const float*)d_in[3];
    const float* W011 = (const float*)d_in[4];
    const float* W101 = (const float*)d_in[5];
    const float* W111 = (const float*)d_in[6];
    float* out = (float*)d_out;

    const int E = in_sizes[0] / 128;

    hipLaunchKernelGGL(prep_weights, dim3((5 * 32768 + 255) / 256), dim3(256), 0, stream,
                       W000, W110, W011, W101, W111, (short*)d_ws);

    const int grid = (E + 31) / 32;
    hipLaunchKernelGGL(e3nn_u4, dim3(grid), dim3(256), 0, stream,
                       x1, x2, (const short8*)d_ws, out, E);
}